// Round 9
// baseline (275.936 us; speedup 1.0000x reference)
//
#include <hip/hip_runtime.h>
#include <hip/hip_bf16.h>
#include <cstdint>
#include <cstddef>

constexpr int B_ = 2, SQ_ = 2048, SK_ = 2048, H_ = 32, HK_ = 8, D_ = 128;
constexpr float SCALE_ = 0.08838834764831845f;  // 1/sqrt(128)

typedef __attribute__((ext_vector_type(4))) float f32x4;
typedef __attribute__((ext_vector_type(8))) short bf16x8;
typedef __attribute__((ext_vector_type(4))) short bf16x4;

__device__ __forceinline__ unsigned short f2bf(float f) {
  union { float f; uint32_t u; } v; v.f = f;
  uint32_t u = v.u;
  return (unsigned short)((u + 0x7FFFu + ((u >> 16) & 1u)) >> 16);  // RNE
}

__device__ __forceinline__ void gload16(const void* g, void* l) {
  __builtin_amdgcn_global_load_lds((const __attribute__((address_space(1))) void*)g,
                                   (__attribute__((address_space(3))) void*)l, 16, 0, 0);
}

// K=16 MFMA: D[m=q:16][n=d:16] += A[m][k:16] * B[n][k:16], fragments k = lg*4+j.
__device__ __forceinline__ f32x4 mfma_k16(bf16x4 a, bf16x4 b, f32x4 c) {
#if __has_builtin(__builtin_amdgcn_mfma_f32_16x16x16bf16_1k)
  return __builtin_amdgcn_mfma_f32_16x16x16bf16_1k(a, b, c, 0, 0, 0);
#else
  bf16x8 a8 = {a[0], a[1], a[2], a[3], 0, 0, 0, 0};
  bf16x8 b8 = {b[0], b[1], b[2], b[3], 0, 0, 0, 0};
  return __builtin_amdgcn_mfma_f32_16x16x32_bf16(a8, b8, c, 0, 0, 0);
#endif
}

// ---- sk_valid per batch (mask dtype sniffed at runtime)
__global__ void skv_kernel(const void* __restrict__ mask, int* __restrict__ skv_out) {
  const int b = blockIdx.x;
  const int tid = threadIdx.x;
  __shared__ int red[256];
  const uint32_t* mw = (const uint32_t*)mask;
  const uint32_t w0 = mw[0], w1 = mw[1];
  int cnt = 0;
  if (w0 > 1u) {
    const uint8_t* m = (const uint8_t*)mask + (size_t)b * SK_;
    for (int s = tid; s < SK_; s += 256) cnt += (m[s] != 0);
  } else if (w1 == 0u) {
    const uint32_t* m = mw + (size_t)b * SK_ * 2;
    for (int s = tid; s < SK_; s += 256) cnt += (m[2 * s] != 0);
  } else {
    const int* m = (const int*)mask + (size_t)b * SK_;
    for (int s = tid; s < SK_; s += 256) cnt += (m[s] != 0);
  }
  red[tid] = cnt;
  __syncthreads();
  for (int o = 128; o > 0; o >>= 1) {
    if (tid < o) red[tid] += red[tid + o];
    __syncthreads();
  }
  if (tid == 0) skv_out[b] = red[0];
}

// ---- mean of V over all SK keys (uniform-softmax degenerate rows)
__global__ void meanv_kernel(const float* __restrict__ kv, float* __restrict__ meanv) {
  const int blk = blockIdx.x;
  const int chunk = blk & 15;
  const int hk = (blk >> 4) & 7;
  const int b = blk >> 7;
  const int d = threadIdx.x;
  float sum = 0.0f;
  for (int i = 0; i < 128; ++i) {
    const int s = chunk * 128 + i;
    sum += kv[((((size_t)b * SK_ + s) * 2 + 1) * HK_ + hk) * D_ + d];
  }
  atomicAdd(meanv + ((size_t)b * HK_ + hk) * D_ + d, sum * (1.0f / (float)SK_));
}

// ---- K: f32 [b][s][0][hk][d] -> bf16 Kb [b][hk][s][d]
__global__ void convk(const float* __restrict__ kv, unsigned short* __restrict__ Kb) {
  const int b = blockIdx.z, hk = blockIdx.y;
  const int s = blockIdx.x * 16 + (threadIdx.x >> 4);
  const int dc = (threadIdx.x & 15) * 8;
  const float* src = kv + ((((size_t)b * SK_ + s) * 2 + 0) * HK_ + hk) * D_ + dc;
  f32x4 a0 = *(const f32x4*)src;
  f32x4 a1 = *(const f32x4*)(src + 4);
  bf16x8 t;
  t[0] = (short)f2bf(a0[0]); t[1] = (short)f2bf(a0[1]);
  t[2] = (short)f2bf(a0[2]); t[3] = (short)f2bf(a0[3]);
  t[4] = (short)f2bf(a1[0]); t[5] = (short)f2bf(a1[1]);
  t[6] = (short)f2bf(a1[2]); t[7] = (short)f2bf(a1[3]);
  *(bf16x8*)(Kb + ((size_t)(b * HK_ + hk) * SK_ + s) * D_ + dc) = t;
}

// ---- V: f32 [b][s][1][hk][d] -> bf16 VTb [b][hk][d][s] (transposed)
__global__ void convvt(const float* __restrict__ kv, unsigned short* __restrict__ VTb) {
  const int b = blockIdx.z, hk = blockIdx.y;
  const int s0 = blockIdx.x * 64;
  const int d = threadIdx.x & 127;
  const int sg = threadIdx.x >> 7;
  unsigned short vals[32];
#pragma unroll
  for (int i = 0; i < 32; ++i) {
    const int s = s0 + sg * 32 + i;
    vals[i] = f2bf(kv[((((size_t)b * SK_ + s) * 2 + 1) * HK_ + hk) * D_ + d]);
  }
  unsigned short* dst = VTb + ((size_t)(b * HK_ + hk) * D_ + d) * SK_ + s0 + sg * 32;
#pragma unroll
  for (int c = 0; c < 4; ++c) {
    bf16x8 t;
#pragma unroll
    for (int i = 0; i < 8; ++i) t[i] = (short)vals[c * 8 + i];
    *(bf16x8*)(dst + c * 8) = t;
  }
}

// ---- flash attention v9: 64 q-rows/block, KV split across wave-pairs,
//      64-key steps single-buffered (32KB LDS), in-LDS flash combine.
__global__ __launch_bounds__(256, 2)
void flash9(const float* __restrict__ q, const unsigned short* __restrict__ Kb,
            const unsigned short* __restrict__ VTb, const int* __restrict__ skv_arr,
            const float* __restrict__ meanv, float* __restrict__ out,
            int* __restrict__ work_ctr) {
  const int tid = threadIdx.x;
  const int w = tid >> 6, l = tid & 63, lg = l >> 4, lr = l & 15;
  const int qh = w & 1;   // q-half: rows qh*32 .. +32
  const int p = w >> 1;   // KV parity: keys s0 + p*32 .. +32

  __shared__ char smem[32768];
  char* kbuf = smem;           // K tile: [key:64][d:128] bf16, swizzled
  char* vbuf = smem + 16384;   // V^T tile: [d:128][key:64] bf16, swizzled

  const int NITEMS = (SQ_ / 64) * H_ * B_;  // 2048

  for (;;) {
    if (tid == 0) *(volatile int*)smem = atomicAdd(work_ctr, 1);
    __syncthreads();
    const int r = *(volatile int*)smem;
    __syncthreads();
    if (r >= NITEMS) break;

    const int qtile = 31 - (r >> 6);   // heaviest first
    const int h = r & 31;
    const int b = (r >> 5) & 1;
    const int hk = h >> 2;
    const int t0 = qtile * 64;
    const int skv = skv_arr[b];

    // Q B-fragments (swapped QK^T): col(q)=lr, k-chunk kk, k-sub lg*8
    bf16x8 qf[2][4];
#pragma unroll
    for (int rb = 0; rb < 2; ++rb) {
      const int trow = t0 + qh * 32 + rb * 16 + lr;
      const float* qp = q + (((size_t)b * SQ_ + trow) * H_ + h) * D_;
#pragma unroll
      for (int kk = 0; kk < 4; ++kk) {
        f32x4 a0 = *(const f32x4*)(qp + kk * 32 + lg * 8);
        f32x4 a1 = *(const f32x4*)(qp + kk * 32 + lg * 8 + 4);
        bf16x8 t;
        t[0] = (short)f2bf(a0[0]); t[1] = (short)f2bf(a0[1]);
        t[2] = (short)f2bf(a0[2]); t[3] = (short)f2bf(a0[3]);
        t[4] = (short)f2bf(a1[0]); t[5] = (short)f2bf(a1[1]);
        t[6] = (short)f2bf(a1[2]); t[7] = (short)f2bf(a1[3]);
        qf[rb][kk] = t;
      }
    }

    f32x4 acc0[8], acc1[8];
#pragma unroll
    for (int i = 0; i < 8; ++i) { acc0[i] = (f32x4)0.0f; acc1[i] = (f32x4)0.0f; }
    float m_[2], l_[2];
#pragma unroll
    for (int rb = 0; rb < 2; ++rb) { m_[rb] = -1e30f; l_[rb] = 0.0f; }

    int n_allowed = t0 + 63 + skv - SQ_ + 1;
    if (n_allowed > skv) n_allowed = skv;
    const int nt = (n_allowed > 0) ? ((n_allowed + 63) >> 6) : 0;

    const char* kgb = (const char*)Kb + ((size_t)(b * HK_ + hk)) * SK_ * D_ * 2;
    const char* vgb = (const char*)VTb + ((size_t)(b * HK_ + hk)) * (size_t)D_ * SK_ * 2;

    for (int j = 0; j < nt; ++j) {
      const int s0 = j * 64;
      // ---- cooperative stage: K 16KB (64 keys x 128d) + V^T 16KB (128d x 64 keys)
      {
        const char* kt = kgb + (size_t)s0 * 256;
#pragma unroll
        for (int i = 0; i < 4; ++i) {
          const int c8 = w * 4 + i;
          const int beta = c8 * 1024 + l * 16;
          const int row = beta >> 8;
          gload16(kt + (beta ^ ((row & 7) << 4)), kbuf + c8 * 1024);
        }
        const char* vt = vgb + s0 * 2;
#pragma unroll
        for (int i = 0; i < 4; ++i) {
          const int c8 = w * 4 + i;
          const int beta = c8 * 1024 + l * 16;
          const int lam = beta ^ (((beta >> 7) & 7) << 4);
          const int d = lam >> 7, keyb = lam & 127;
          gload16(vt + (size_t)d * (SK_ * 2) + keyb, vbuf + c8 * 1024);
        }
      }
      asm volatile("s_waitcnt vmcnt(0)" ::: "memory");
      __builtin_amdgcn_s_barrier();

      // ---- S^T = K Q^T on this wave's 32-key window (rows p*32..)
      f32x4 sc[2][2];
      sc[0][0] = (f32x4)0.0f; sc[0][1] = (f32x4)0.0f;
      sc[1][0] = (f32x4)0.0f; sc[1][1] = (f32x4)0.0f;
#pragma unroll
      for (int c = 0; c < 2; ++c) {
        const int row = p * 32 + c * 16 + lr;
        const int kx = (row & 7) << 4;
#pragma unroll
        for (int kk = 0; kk < 4; ++kk) {
          const int byte = (row << 8) + ((kk * 32 + lg * 8) << 1);
          bf16x8 kf = *(const bf16x8*)(kbuf + (byte ^ kx));
          sc[0][c] = __builtin_amdgcn_mfma_f32_16x16x32_bf16(kf, qf[0][kk], sc[0][c], 0, 0, 0);
          sc[1][c] = __builtin_amdgcn_mfma_f32_16x16x32_bf16(kf, qf[1][kk], sc[1][c], 0, 0, 0);
        }
      }

      // ---- mask + online softmax, in-register (row = q = lr per lane)
      const int kbase = s0 + p * 32 + (lg << 2);
      float al_[2];
#pragma unroll
      for (int rb = 0; rb < 2; ++rb) {
        const int lim = t0 + qh * 32 + rb * 16 + lr + skv - SQ_;
        float mx = -1e30f;
#pragma unroll
        for (int c = 0; c < 2; ++c)
#pragma unroll
          for (int rr = 0; rr < 4; ++rr) {
            const int key = kbase + c * 16 + rr;
            float sv = (key <= lim) ? sc[rb][c][rr] * SCALE_ : -1e30f;
            sc[rb][c][rr] = sv;
            mx = fmaxf(mx, sv);
          }
        mx = fmaxf(mx, __shfl_xor(mx, 16));
        mx = fmaxf(mx, __shfl_xor(mx, 32));
        const float mn = fmaxf(m_[rb], mx);
        al_[rb] = __expf(m_[rb] - mn);
        m_[rb] = mn;
        float ps = 0.0f;
#pragma unroll
        for (int c = 0; c < 2; ++c)
#pragma unroll
          for (int rr = 0; rr < 4; ++rr) {
            const float pv = __expf(sc[rb][c][rr] - mn);
            sc[rb][c][rr] = pv;
            ps += pv;
          }
        ps += __shfl_xor(ps, 16);
        ps += __shfl_xor(ps, 32);
        l_[rb] = l_[rb] * al_[rb] + ps;
      }

      // ---- rescale acc (alpha at q=lr -> rows q=lg*4+rr)
      float alq0[4], alq1[4];
#pragma unroll
      for (int rr = 0; rr < 4; ++rr) {
        alq0[rr] = __shfl(al_[0], lg * 4 + rr, 16);
        alq1[rr] = __shfl(al_[1], lg * 4 + rr, 16);
      }
#pragma unroll
      for (int dd = 0; dd < 8; ++dd)
#pragma unroll
        for (int rr = 0; rr < 4; ++rr) { acc0[dd][rr] *= alq0[rr]; acc1[dd][rr] *= alq1[rr]; }

      // ---- P in-register K=16 A-fragments
      bf16x4 pa[2][2];
#pragma unroll
      for (int rb = 0; rb < 2; ++rb)
#pragma unroll
        for (int c = 0; c < 2; ++c) {
          const f32x4 s4 = rb ? sc[1][c] : sc[0][c];
          bf16x4 t;
          t[0] = (short)f2bf(s4[0]); t[1] = (short)f2bf(s4[1]);
          t[2] = (short)f2bf(s4[2]); t[3] = (short)f2bf(s4[3]);
          pa[rb][c] = t;
        }

      // ---- O += P V (V^T rows d, this wave's key window p*64 byte offset)
#pragma unroll
      for (int dd = 0; dd < 8; ++dd) {
        const int d = dd * 16 + lr;
#pragma unroll
        for (int c = 0; c < 2; ++c) {
          const int lam = d * 128 + p * 64 + c * 32 + lg * 8;
          bf16x4 vf = *(const bf16x4*)(vbuf + (lam ^ ((d & 7) << 4)));
          acc0[dd] = mfma_k16(pa[0][c], vf, acc0[dd]);
          acc1[dd] = mfma_k16(pa[1][c], vf, acc1[dd]);
        }
      }
      asm volatile("" ::: "memory");
      __builtin_amdgcn_s_barrier();  // all reads done before next stage
    }

    // ---- combine the two KV-halves (waves w and w^2, same qh) ----
    // C1: exchange m,l
    {
      float* ml = (float*)(smem) + w * 256 + l * 4;
      ml[0] = m_[0]; ml[1] = m_[1]; ml[2] = l_[0]; ml[3] = l_[1];
    }
    __syncthreads();
    float a_[2], lstar[2];
    {
      const float* pml = (const float*)(smem) + (w ^ 2) * 256 + l * 4;
      const float pm0 = pml[0], pm1 = pml[1], pl0 = pml[2], pl1 = pml[3];
      float ms0 = fmaxf(m_[0], pm0), ms1 = fmaxf(m_[1], pm1);
      a_[0] = __expf(m_[0] - ms0); a_[1] = __expf(m_[1] - ms1);
      lstar[0] = a_[0] * l_[0] + __expf(pm0 - ms0) * pl0;
      lstar[1] = a_[1] * l_[1] + __expf(pm1 - ms1) * pl1;
    }
    __syncthreads();  // ml region consumed
    // scale own acc by a_ (redistribute to rows q=lg*4+rr)
    {
      float aq0[4], aq1[4];
#pragma unroll
      for (int rr = 0; rr < 4; ++rr) {
        aq0[rr] = __shfl(a_[0], lg * 4 + rr, 16);
        aq1[rr] = __shfl(a_[1], lg * 4 + rr, 16);
      }
#pragma unroll
      for (int dd = 0; dd < 8; ++dd)
#pragma unroll
        for (int rr = 0; rr < 4; ++rr) { acc0[dd][rr] *= aq0[rr]; acc1[dd][rr] *= aq1[rr]; }
    }
    // C2: parity-1 waves publish scaled acc; parity-0 waves merge + write out
    {
      char* ex = smem + (qh << 14);
      if (p == 1) {
#pragma unroll
        for (int i = 0; i < 8; ++i) {
          const int b0 = (l << 8) + (i << 4);
          const int b1 = (l << 8) + ((i + 8) << 4);
          *(f32x4*)(ex + (b0 ^ ((l & 7) << 4))) = acc0[i];
          *(f32x4*)(ex + (b1 ^ ((l & 7) << 4))) = acc1[i];
        }
      }
    }
    __syncthreads();
    if (p == 0) {
      const char* ex = smem + (qh << 14);
#pragma unroll
      for (int i = 0; i < 8; ++i) {
        const int b0 = (l << 8) + (i << 4);
        const int b1 = (l << 8) + ((i + 8) << 4);
        acc0[i] += *(const f32x4*)(ex + (b0 ^ ((l & 7) << 4)));
        acc1[i] += *(const f32x4*)(ex + (b1 ^ ((l & 7) << 4)));
      }
      // ---- epilogue (lstar at q=lr; acc rows q=lg*4+rr)
      const float* mp = meanv + ((size_t)(b * HK_ + hk)) * D_;
#pragma unroll
      for (int rb = 0; rb < 2; ++rb) {
        const f32x4* acc = rb ? acc1 : acc0;
        const float lsrc = rb ? lstar[1] : lstar[0];
#pragma unroll
        for (int rr = 0; rr < 4; ++rr) {
          const float lq = __shfl(lsrc, lg * 4 + rr, 16);
          const int t_r = t0 + qh * 32 + rb * 16 + lg * 4 + rr;
          const bool deg = (t_r + skv - SQ_) < 0;
          const float inv = 1.0f / lq;
          float* op = out + (((size_t)b * SQ_ + t_r) * H_ + h) * D_;
#pragma unroll
          for (int dd = 0; dd < 8; ++dd) {
            const int d = dd * 16 + lr;
            op[d] = deg ? mp[d] : acc[dd][rr] * inv;
          }
        }
      }
    }
    __syncthreads();  // all waves done before next item's broadcast/staging
  }
}

extern "C" void kernel_launch(void* const* d_in, const int* in_sizes, int n_in,
                              void* d_out, int out_size, void* d_ws, size_t ws_size,
                              hipStream_t stream) {
  const float* q = (const float*)d_in[0];
  const float* kv = (const float*)d_in[1];
  const void* mask = d_in[2];
  float* out = (float*)d_out;

  const size_t KB_OFF = 0;
  const size_t VT_OFF = 8ull * 1024 * 1024;
  const size_t MV_OFF = 16ull * 1024 * 1024;
  unsigned short* Kb = (unsigned short*)((char*)d_ws + KB_OFF);
  unsigned short* VTb = (unsigned short*)((char*)d_ws + VT_OFF);
  float* meanv = (float*)((char*)d_ws + MV_OFF);
  int* skv = (int*)((char*)d_ws + MV_OFF + 8192);
  int* work_ctr = (int*)((char*)d_ws + MV_OFF + 8192 + 64);

  hipMemsetAsync((char*)d_ws + MV_OFF, 0, 8192 + 128, stream);
  skv_kernel<<<B_, 256, 0, stream>>>(mask, skv);
  convk<<<dim3(SK_ / 16, HK_, B_), 256, 0, stream>>>(kv, Kb);
  convvt<<<dim3(SK_ / 64, HK_, B_), 256, 0, stream>>>(kv, VTb);
  meanv_kernel<<<B_ * HK_ * 16, 128, 0, stream>>>(kv, meanv);
  flash9<<<dim3(1024), 256, 0, stream>>>(q, Kb, VTb, skv, meanv, out, work_ctr);
}

// Round 10
// 182.756 us; speedup vs baseline: 1.5099x; 1.5099x over previous
//
#include <hip/hip_runtime.h>
#include <hip/hip_bf16.h>
#include <cstdint>
#include <cstddef>

constexpr int B_ = 2, SQ_ = 2048, SK_ = 2048, H_ = 32, HK_ = 8, D_ = 128;
constexpr float SCALE_ = 0.08838834764831845f;  // 1/sqrt(128)

typedef __attribute__((ext_vector_type(4))) float f32x4;
typedef __attribute__((ext_vector_type(8))) short bf16x8;
typedef __attribute__((ext_vector_type(4))) short bf16x4;

__device__ __forceinline__ unsigned short f2bf(float f) {
  union { float f; uint32_t u; } v; v.f = f;
  uint32_t u = v.u;
  return (unsigned short)((u + 0x7FFFu + ((u >> 16) & 1u)) >> 16);  // RNE
}

__device__ __forceinline__ void gload16(const void* g, void* l) {
  __builtin_amdgcn_global_load_lds((const __attribute__((address_space(1))) void*)g,
                                   (__attribute__((address_space(3))) void*)l, 16, 0, 0);
}

// K=16 MFMA: D[m=q:16][n=d:16] += A[m][k:16] * B[n][k:16], fragments k = lg*4+j.
__device__ __forceinline__ f32x4 mfma_k16(bf16x4 a, bf16x4 b, f32x4 c) {
#if __has_builtin(__builtin_amdgcn_mfma_f32_16x16x16bf16_1k)
  return __builtin_amdgcn_mfma_f32_16x16x16bf16_1k(a, b, c, 0, 0, 0);
#else
  bf16x8 a8 = {a[0], a[1], a[2], a[3], 0, 0, 0, 0};
  bf16x8 b8 = {b[0], b[1], b[2], b[3], 0, 0, 0, 0};
  return __builtin_amdgcn_mfma_f32_16x16x32_bf16(a8, b8, c, 0, 0, 0);
#endif
}

// ---- sk_valid per batch (mask dtype sniffed at runtime)
__global__ void skv_kernel(const void* __restrict__ mask, int* __restrict__ skv_out) {
  const int b = blockIdx.x;
  const int tid = threadIdx.x;
  __shared__ int red[256];
  const uint32_t* mw = (const uint32_t*)mask;
  const uint32_t w0 = mw[0], w1 = mw[1];
  int cnt = 0;
  if (w0 > 1u) {
    const uint8_t* m = (const uint8_t*)mask + (size_t)b * SK_;
    for (int s = tid; s < SK_; s += 256) cnt += (m[s] != 0);
  } else if (w1 == 0u) {
    const uint32_t* m = mw + (size_t)b * SK_ * 2;
    for (int s = tid; s < SK_; s += 256) cnt += (m[2 * s] != 0);
  } else {
    const int* m = (const int*)mask + (size_t)b * SK_;
    for (int s = tid; s < SK_; s += 256) cnt += (m[s] != 0);
  }
  red[tid] = cnt;
  __syncthreads();
  for (int o = 128; o > 0; o >>= 1) {
    if (tid < o) red[tid] += red[tid + o];
    __syncthreads();
  }
  if (tid == 0) skv_out[b] = red[0];
}

// ---- mean of V over all SK keys (uniform-softmax degenerate rows)
__global__ void meanv_kernel(const float* __restrict__ kv, float* __restrict__ meanv) {
  const int blk = blockIdx.x;
  const int chunk = blk & 15;
  const int hk = (blk >> 4) & 7;
  const int b = blk >> 7;
  const int d = threadIdx.x;
  float sum = 0.0f;
  for (int i = 0; i < 128; ++i) {
    const int s = chunk * 128 + i;
    sum += kv[((((size_t)b * SK_ + s) * 2 + 1) * HK_ + hk) * D_ + d];
  }
  atomicAdd(meanv + ((size_t)b * HK_ + hk) * D_ + d, sum * (1.0f / (float)SK_));
}

// ---- K: f32 [b][s][0][hk][d] -> bf16 Kb [b][hk][s][d]
__global__ void convk(const float* __restrict__ kv, unsigned short* __restrict__ Kb) {
  const int b = blockIdx.z, hk = blockIdx.y;
  const int s = blockIdx.x * 16 + (threadIdx.x >> 4);
  const int dc = (threadIdx.x & 15) * 8;
  const float* src = kv + ((((size_t)b * SK_ + s) * 2 + 0) * HK_ + hk) * D_ + dc;
  f32x4 a0 = *(const f32x4*)src;
  f32x4 a1 = *(const f32x4*)(src + 4);
  bf16x8 t;
  t[0] = (short)f2bf(a0[0]); t[1] = (short)f2bf(a0[1]);
  t[2] = (short)f2bf(a0[2]); t[3] = (short)f2bf(a0[3]);
  t[4] = (short)f2bf(a1[0]); t[5] = (short)f2bf(a1[1]);
  t[6] = (short)f2bf(a1[2]); t[7] = (short)f2bf(a1[3]);
  *(bf16x8*)(Kb + ((size_t)(b * HK_ + hk) * SK_ + s) * D_ + dc) = t;
}

// ---- V: f32 [b][s][1][hk][d] -> bf16 VTb [b][hk][d][s] (transposed)
__global__ void convvt(const float* __restrict__ kv, unsigned short* __restrict__ VTb) {
  const int b = blockIdx.z, hk = blockIdx.y;
  const int s0 = blockIdx.x * 64;
  const int d = threadIdx.x & 127;
  const int sg = threadIdx.x >> 7;
  unsigned short vals[32];
#pragma unroll
  for (int i = 0; i < 32; ++i) {
    const int s = s0 + sg * 32 + i;
    vals[i] = f2bf(kv[((((size_t)b * SK_ + s) * 2 + 1) * HK_ + hk) * D_ + d]);
  }
  unsigned short* dst = VTb + ((size_t)(b * HK_ + hk) * D_ + d) * SK_ + s0 + sg * 32;
#pragma unroll
  for (int c = 0; c < 4; ++c) {
    bf16x8 t;
#pragma unroll
    for (int i = 0; i < 8; ++i) t[i] = (short)vals[c * 8 + i];
    *(bf16x8*)(dst + c * 8) = t;
  }
}

// ---- flash attention v10: GQA 4-head sharing, KVBLK=64 double-buffered,
//      in-register P, defer-max. 64KB LDS, grid 512, LPT queue of 1024 items.
__global__ __launch_bounds__(256, 2)
void flash10(const float* __restrict__ q, const unsigned short* __restrict__ Kb,
             const unsigned short* __restrict__ VTb, const int* __restrict__ skv_arr,
             const float* __restrict__ meanv, float* __restrict__ out,
             int* __restrict__ work_ctr) {
  const int tid = threadIdx.x;
  const int w = tid >> 6, l = tid & 63, lg = l >> 4, lr = l & 15;

  __shared__ char smem[65536];
  char* kc0 = smem;          char* vc0 = smem + 16384;
  char* kn0 = smem + 32768;  char* vn0 = smem + 49152;

  const int NITEMS = (SQ_ / 32) * HK_ * B_;  // 1024

  for (;;) {
    if (tid == 0) *(volatile int*)smem = atomicAdd(work_ctr, 1);
    __syncthreads();
    const int r = *(volatile int*)smem;
    __syncthreads();
    if (r >= NITEMS) break;

    const int qt = 63 - (r >> 4);   // heaviest first (LPT)
    const int hk = (r >> 1) & 7;
    const int b = r & 1;
    const int h = hk * 4 + w;       // each wave: one q-head of the GQA group
    const int t0 = qt * 32;
    const int skv = skv_arr[b];

    char* kc = kc0; char* kn = kn0; char* vc = vc0; char* vn = vn0;

    // Q B-fragments (swapped QK^T): col(q)=lr, k-chunk kk, k-sub lg*8
    bf16x8 qf[2][4];
#pragma unroll
    for (int rb = 0; rb < 2; ++rb) {
      const int trow = t0 + rb * 16 + lr;
      const float* qp = q + (((size_t)b * SQ_ + trow) * H_ + h) * D_;
#pragma unroll
      for (int kk = 0; kk < 4; ++kk) {
        f32x4 a0 = *(const f32x4*)(qp + kk * 32 + lg * 8);
        f32x4 a1 = *(const f32x4*)(qp + kk * 32 + lg * 8 + 4);
        bf16x8 t;
        t[0] = (short)f2bf(a0[0]); t[1] = (short)f2bf(a0[1]);
        t[2] = (short)f2bf(a0[2]); t[3] = (short)f2bf(a0[3]);
        t[4] = (short)f2bf(a1[0]); t[5] = (short)f2bf(a1[1]);
        t[6] = (short)f2bf(a1[2]); t[7] = (short)f2bf(a1[3]);
        qf[rb][kk] = t;
      }
    }

    f32x4 acc0[8], acc1[8];
#pragma unroll
    for (int i = 0; i < 8; ++i) { acc0[i] = (f32x4)0.0f; acc1[i] = (f32x4)0.0f; }
    float m_[2], l_[2];
#pragma unroll
    for (int rb = 0; rb < 2; ++rb) { m_[rb] = -1e30f; l_[rb] = 0.0f; }

    int n_allowed = t0 + 31 + skv - SQ_ + 1;
    if (n_allowed > skv) n_allowed = skv;
    const int nt = (n_allowed > 0) ? ((n_allowed + 63) >> 6) : 0;

    const char* kgb = (const char*)Kb + ((size_t)(b * HK_ + hk)) * SK_ * D_ * 2;
    const char* vgb = (const char*)VTb + ((size_t)(b * HK_ + hk)) * (size_t)D_ * SK_ * 2;

    // 16KB K tile (64 keys x 128 d) + 16KB V^T tile (128 d x 64 keys), 8 loads/wave
    auto stage = [&](char* kdst, char* vdst, int s0) {
      const char* kt = kgb + (size_t)s0 * 256;
#pragma unroll
      for (int i = 0; i < 4; ++i) {
        const int c8 = w * 4 + i;
        const int beta = c8 * 1024 + l * 16;
        const int row = beta >> 8;
        gload16(kt + (beta ^ ((row & 7) << 4)), kdst + c8 * 1024);
      }
      const char* vt = vgb + s0 * 2;
#pragma unroll
      for (int i = 0; i < 4; ++i) {
        const int c8 = w * 4 + i;
        const int beta = c8 * 1024 + l * 16;
        const int lam = beta ^ (((beta >> 7) & 7) << 4);
        const int d = lam >> 7, keyb = lam & 127;
        gload16(vt + (size_t)d * (SK_ * 2) + keyb, vdst + c8 * 1024);
      }
    };

    asm volatile("s_waitcnt vmcnt(0)" ::: "memory");
    if (nt > 0) stage(kc, vc, 0);

    for (int j = 0; j < nt; ++j) {
      if (j + 1 < nt) {
        stage(kn, vn, (j + 1) * 64);
        asm volatile("s_waitcnt vmcnt(8)" ::: "memory");
      } else {
        asm volatile("s_waitcnt vmcnt(0)" ::: "memory");
      }
      __builtin_amdgcn_s_barrier();

      const int s0 = j * 64;
      // ---- S^T = K Q^T: sc[rb][c][rr] = S[key=s0+c*16+lg*4+rr][q=t0+rb*16+lr]
      f32x4 sc[2][4];
#pragma unroll
      for (int c = 0; c < 4; ++c) { sc[0][c] = (f32x4)0.0f; sc[1][c] = (f32x4)0.0f; }
#pragma unroll
      for (int c = 0; c < 4; ++c) {
        const int row = c * 16 + lr;
        const int kx = (row & 7) << 4;
#pragma unroll
        for (int kk = 0; kk < 4; ++kk) {
          const int byte = (row << 8) + ((kk * 32 + lg * 8) << 1);
          bf16x8 kf = *(const bf16x8*)(kc + (byte ^ kx));
          sc[0][c] = __builtin_amdgcn_mfma_f32_16x16x32_bf16(kf, qf[0][kk], sc[0][c], 0, 0, 0);
          sc[1][c] = __builtin_amdgcn_mfma_f32_16x16x32_bf16(kf, qf[1][kk], sc[1][c], 0, 0, 0);
        }
      }

      // ---- mask + per-row max (row = q = lr per lane)
      const int kbase = s0 + (lg << 2);
      float pmax[2];
#pragma unroll
      for (int rb = 0; rb < 2; ++rb) {
        const int lim = t0 + rb * 16 + lr + skv - SQ_;
        float mx = -1e30f;
#pragma unroll
        for (int c = 0; c < 4; ++c)
#pragma unroll
          for (int rr = 0; rr < 4; ++rr) {
            const int key = kbase + c * 16 + rr;
            float sv = (key <= lim) ? sc[rb][c][rr] * SCALE_ : -1e30f;
            sc[rb][c][rr] = sv;
            mx = fmaxf(mx, sv);
          }
        mx = fmaxf(mx, __shfl_xor(mx, 16));
        mx = fmaxf(mx, __shfl_xor(mx, 32));
        pmax[rb] = mx;
      }

      // ---- defer-max: rescale only when the running max grew by > 8
      const float worst = fmaxf(pmax[0] - m_[0], pmax[1] - m_[1]);
      if (!__all(worst <= 8.0f)) {
        float al_[2];
#pragma unroll
        for (int rb = 0; rb < 2; ++rb) {
          const float mn = fmaxf(m_[rb], pmax[rb]);
          al_[rb] = __expf(m_[rb] - mn);
          m_[rb] = mn;
          l_[rb] *= al_[rb];
        }
        float alq0[4], alq1[4];
#pragma unroll
        for (int rr = 0; rr < 4; ++rr) {
          alq0[rr] = __shfl(al_[0], lg * 4 + rr, 16);
          alq1[rr] = __shfl(al_[1], lg * 4 + rr, 16);
        }
#pragma unroll
        for (int dd = 0; dd < 8; ++dd)
#pragma unroll
          for (int rr = 0; rr < 4; ++rr) { acc0[dd][rr] *= alq0[rr]; acc1[dd][rr] *= alq1[rr]; }
      }

      // ---- P = exp(S - m), row-sum into l_
#pragma unroll
      for (int rb = 0; rb < 2; ++rb) {
        float ps = 0.0f;
#pragma unroll
        for (int c = 0; c < 4; ++c)
#pragma unroll
          for (int rr = 0; rr < 4; ++rr) {
            const float pv = __expf(sc[rb][c][rr] - m_[rb]);
            sc[rb][c][rr] = pv;
            ps += pv;
          }
        ps += __shfl_xor(ps, 16);
        ps += __shfl_xor(ps, 32);
        l_[rb] += ps;
      }

      // ---- P in-register K=16 A-fragments
      bf16x4 pa[2][4];
#pragma unroll
      for (int rb = 0; rb < 2; ++rb)
#pragma unroll
        for (int c = 0; c < 4; ++c) {
          const f32x4 s4 = rb ? sc[1][c] : sc[0][c];
          bf16x4 t;
          t[0] = (short)f2bf(s4[0]); t[1] = (short)f2bf(s4[1]);
          t[2] = (short)f2bf(s4[2]); t[3] = (short)f2bf(s4[3]);
          pa[rb][c] = t;
        }

      // ---- O += P V (V^T rows d; 4 K=16 chunks)
#pragma unroll
      for (int dd = 0; dd < 8; ++dd) {
        const int d = dd * 16 + lr;
#pragma unroll
        for (int c = 0; c < 4; ++c) {
          const int lam = d * 128 + c * 32 + lg * 8;
          bf16x4 vf = *(const bf16x4*)(vc + (lam ^ ((d & 7) << 4)));
          acc0[dd] = mfma_k16(pa[0][c], vf, acc0[dd]);
          acc1[dd] = mfma_k16(pa[1][c], vf, acc1[dd]);
        }
      }
      asm volatile("" ::: "memory");
      __builtin_amdgcn_s_barrier();
      { char* t = kc; kc = kn; kn = t; t = vc; vc = vn; vn = t; }
    }

    // ---- epilogue (l_ at q=lr; acc rows q=lg*4+rr)
    const float* mp = meanv + ((size_t)(b * HK_ + hk)) * D_;
#pragma unroll
    for (int rb = 0; rb < 2; ++rb) {
      const f32x4* acc = rb ? acc1 : acc0;
      const float lsrc = rb ? l_[1] : l_[0];
#pragma unroll
      for (int rr = 0; rr < 4; ++rr) {
        const float lq = __shfl(lsrc, lg * 4 + rr, 16);
        const int t_r = t0 + rb * 16 + lg * 4 + rr;
        const bool deg = (t_r + skv - SQ_) < 0;
        const float inv = 1.0f / lq;
        float* op = out + (((size_t)b * SQ_ + t_r) * H_ + h) * D_;
#pragma unroll
        for (int dd = 0; dd < 8; ++dd) {
          const int d = dd * 16 + lr;
          op[d] = deg ? mp[d] : acc[dd][rr] * inv;
        }
      }
    }
    __syncthreads();  // all waves done with LDS before next item's broadcast
  }
}

extern "C" void kernel_launch(void* const* d_in, const int* in_sizes, int n_in,
                              void* d_out, int out_size, void* d_ws, size_t ws_size,
                              hipStream_t stream) {
  const float* q = (const float*)d_in[0];
  const float* kv = (const float*)d_in[1];
  const void* mask = d_in[2];
  float* out = (float*)d_out;

  const size_t KB_OFF = 0;
  const size_t VT_OFF = 8ull * 1024 * 1024;
  const size_t MV_OFF = 16ull * 1024 * 1024;
  unsigned short* Kb = (unsigned short*)((char*)d_ws + KB_OFF);
  unsigned short* VTb = (unsigned short*)((char*)d_ws + VT_OFF);
  float* meanv = (float*)((char*)d_ws + MV_OFF);
  int* skv = (int*)((char*)d_ws + MV_OFF + 8192);
  int* work_ctr = (int*)((char*)d_ws + MV_OFF + 8192 + 64);

  hipMemsetAsync((char*)d_ws + MV_OFF, 0, 8192 + 128, stream);
  skv_kernel<<<B_, 256, 0, stream>>>(mask, skv);
  convk<<<dim3(SK_ / 16, HK_, B_), 256, 0, stream>>>(kv, Kb);
  convvt<<<dim3(SK_ / 64, HK_, B_), 256, 0, stream>>>(kv, VTb);
  meanv_kernel<<<B_ * HK_ * 16, 128, 0, stream>>>(kv, meanv);
  flash10<<<dim3(512), 256, 0, stream>>>(q, Kb, VTb, skv, meanv, out, work_ctr);
}